// Round 1
// baseline (96.054 us; speedup 1.0000x reference)
//
#include <hip/hip_runtime.h>
#include <hip/hip_bf16.h>

#define NN 8192
#define DD 256
#define HH 64
#define DEG 32

typedef __attribute__((ext_vector_type(8))) short short8;   // 8 bf16
typedef __attribute__((ext_vector_type(4))) float f32x4;

static __device__ __forceinline__ unsigned short f2b(float f) {
    __hip_bfloat16 h = __float2bfloat16(f);   // RNE
    return *(unsigned short*)&h;
}
static __device__ __forceinline__ float b2f(unsigned short u) {
    unsigned int v = ((unsigned int)u) << 16;
    float out;
    __builtin_memcpy(&out, &v, 4);
    return out;
}

// ---------------- Kernel 0: build Wt bf16 [192][256] ----------------
// Wt[c][d] = W_{c/64}[d][c%64]  (transposed, bf16)
// 96 blocks x 64 thr: block = sel*32 + dgroup. Lane = c -> coalesced 256B
// reads of W rows (was: 24 blocks, 2KB-stride scatter reads).
__global__ __launch_bounds__(64) void prepw_kernel(
    const float* __restrict__ Wq, const float* __restrict__ Wk, const float* __restrict__ Wv,
    unsigned short* __restrict__ Wt)
{
    const int b = blockIdx.x;
    const int sel = b >> 5, dg = b & 31;              // dg: 8-wide d chunk
    const float* W = (sel == 0) ? Wq : (sel == 1) ? Wk : Wv;
    const int c = threadIdx.x;                        // 0..63 output column
    short8 o;
#pragma unroll
    for (int j = 0; j < 8; j++)
        o[j] = f2b(W[(dg * 8 + j) * HH + c]);         // lanes read consecutive c
    *(short8*)(Wt + (size_t)(sel * 64 + c) * DD + dg * 8) = o;
}

// ---------------- Kernel 1: QKV GEMM via MFMA, K split over 4 waves ----------------
// 2048 blocks x 256 threads (4 waves). Output tile 16 rows x 48 cols per block.
// Wave w handles K range [w*64, w*64+64) -> 2 MFMA k-steps; partials reduced in LDS.
// Occupancy: 8192 waves = 8/SIMD (was 2048 waves = 2/SIMD, latency-exposed).
// bid&511 -> m-group, bid>>9 -> n-band (n-duplicates of an m-group share XCD).
__global__ __launch_bounds__(256) void gemm_kernel(
    const float* __restrict__ x, const unsigned short* __restrict__ Wt,
    const float* __restrict__ bq, const float* __restrict__ bk,
    float* __restrict__ Q, unsigned short* __restrict__ Kb, unsigned short* __restrict__ Vb)
{
    __shared__ float part[4][768];   // 12 KB: per-wave 16x48 partial tiles
    const int bid = blockIdx.x;
    const int m0 = (bid & 511) * 16;
    const int n0 = (bid >> 9) * 48;
    const int w    = threadIdx.x >> 6;
    const int lane = threadIdx.x & 63;
    const int l15 = lane & 15, quad = lane >> 4;

    const float*          arow = x  + (size_t)(m0 + l15) * DD + w * 64 + quad * 8;
    const unsigned short* b0p  = Wt + (size_t)(n0 + l15) * DD + w * 64 + quad * 8;
    const unsigned short* b1p  = b0p + 16 * DD;
    const unsigned short* b2p  = b0p + 32 * DD;

    f32x4 acc0 = {0.f,0.f,0.f,0.f}, acc1 = {0.f,0.f,0.f,0.f}, acc2 = {0.f,0.f,0.f,0.f};

#pragma unroll
    for (int ks = 0; ks < 2; ks++) {
        const int k0 = ks * 32;
        float4 xa = *(const float4*)(arow + k0);
        float4 xb = *(const float4*)(arow + k0 + 4);
        short8 a;
        a[0] = f2b(xa.x); a[1] = f2b(xa.y); a[2] = f2b(xa.z); a[3] = f2b(xa.w);
        a[4] = f2b(xb.x); a[5] = f2b(xb.y); a[6] = f2b(xb.z); a[7] = f2b(xb.w);
        short8 b0 = *(const short8*)(b0p + k0);
        short8 b1 = *(const short8*)(b1p + k0);
        short8 b2 = *(const short8*)(b2p + k0);
        acc0 = __builtin_amdgcn_mfma_f32_16x16x32_bf16(a, b0, acc0, 0, 0, 0);
        acc1 = __builtin_amdgcn_mfma_f32_16x16x32_bf16(a, b1, acc1, 0, 0, 0);
        acc2 = __builtin_amdgcn_mfma_f32_16x16x32_bf16(a, b2, acc2, 0, 0, 0);
    }

    // Deposit partials. C layout: col = nt*16+l15, row = quad*4+r
    const f32x4 accs[3] = {acc0, acc1, acc2};
#pragma unroll
    for (int nt = 0; nt < 3; nt++)
#pragma unroll
        for (int r = 0; r < 4; r++)
            part[w][(quad * 4 + r) * 48 + nt * 16 + l15] = accs[nt][r];
    __syncthreads();

    // Reduce 4 partials + bias + convert + store. 768 outputs / 256 threads = 3 each.
    const int t = threadIdx.x;
#pragma unroll
    for (int e = 0; e < 3; e++) {
        const int f = t * 3 + e;
        const int row = f / 48, col = f % 48;
        float v = part[0][f] + part[1][f] + part[2][f] + part[3][f];
        const int cg = n0 + col;
        const size_t ro = (size_t)(m0 + row) * HH;
        if (cg < 64) {
            Q[ro + cg] = v + bq[cg];
        } else if (cg < 128) {
            const int c = cg - 64;
            Kb[ro + c] = f2b(v + bk[c]);
        } else {
            const int c = cg - 128;
            Vb[ro + c] = f2b(v);
        }
    }
}

// ---------------- Kernel 2: sparse attention ----------------
// 2048 blocks x 256 threads: 4 nodes per block, one wave per node (independent,
// per-wave LDS slices; __syncthreads only orders the symmetric waves).
// Phase2 lane=(k,half): one edge dot per lane pair.
// Phase3 lane=(kg,hg): short8 (16B) V loads, shfl-tree reduce over 8 k-groups.
__global__ __launch_bounds__(256) void attn_kernel(
    const float* __restrict__ Q,
    const unsigned short* __restrict__ Kb, const unsigned short* __restrict__ Vb,
    const int* __restrict__ edge_type, const float* __restrict__ ek_emb,
    float* __restrict__ out)
{
    __shared__ float q[4][HH];
    __shared__ float p[4][DEG];

    const int wv   = threadIdx.x >> 6;
    const int lane = threadIdx.x & 63;
    const int i = blockIdx.x * 4 + wv;
    const int k = lane >> 1, half = lane & 1;

    // issue all global loads early
    q[wv][lane] = Q[(size_t)i * HH + lane];
    const int et = edge_type[i * DEG + k];          // pair-duplicated, coalesced
    const float ekv = ek_emb[et];
    const int j = (i + 37 * (k + 1)) & (NN - 1);
    const unsigned short* kr = Kb + (size_t)j * HH + half * 32;
    short8 kv[4];
    kv[0] = *(const short8*)(kr);
    kv[1] = *(const short8*)(kr + 8);
    kv[2] = *(const short8*)(kr + 16);
    kv[3] = *(const short8*)(kr + 24);
    __syncthreads();

    // dot: lane covers h = half*32 .. half*32+31
    const float4* q4 = (const float4*)(q[wv] + half * 32);
    float s = 0.f;
#pragma unroll
    for (int c8 = 0; c8 < 4; c8++) {
        float4 qa = q4[c8 * 2];
        float4 qb = q4[c8 * 2 + 1];
        short8 kk = kv[c8];
        s += qa.x * b2f(kk[0]) + qa.y * b2f(kk[1]) + qa.z * b2f(kk[2]) + qa.w * b2f(kk[3]);
        s += qb.x * b2f(kk[4]) + qb.y * b2f(kk[5]) + qb.z * b2f(kk[6]) + qb.w * b2f(kk[7]);
    }
    s += __shfl_xor(s, 1);                  // pair-complete dot, duplicated in pair
    s = (s + ekv) * (1.0f / 512.0f);

    // softmax across the 32 ks. Butterfly over xor {2,4,8,16,32} stays within
    // one lane-parity group, and each parity group holds every k EXACTLY ONCE.
    float m = s;
#pragma unroll
    for (int off = 2; off <= 32; off <<= 1)
        m = fmaxf(m, __shfl_xor(m, off));
    float e = __expf(s - m);
    float sum = e;
#pragma unroll
    for (int off = 2; off <= 32; off <<= 1)
        sum += __shfl_xor(sum, off);
    float pk = e / sum;
    if (!half) p[wv][k] = pk;
    __syncthreads();

    // V pass: lane = (kg, hg). kg group handles k = kg*4..kg*4+3, hg covers 8 h.
    // Loads: 8 lanes (hg=0..7, same kg) read one 128B V row -> fully coalesced.
    const int hg = lane & 7, kg = lane >> 3;
    float acc[8] = {0.f,0.f,0.f,0.f,0.f,0.f,0.f,0.f};
#pragma unroll
    for (int t = 0; t < 4; t++) {
        const int kk = kg * 4 + t;
        const int jj = (i + 37 * (kk + 1)) & (NN - 1);
        short8 v8 = *(const short8*)(Vb + (size_t)jj * HH + hg * 8);
        const float wgt = p[wv][kk];
#pragma unroll
        for (int e2 = 0; e2 < 8; e2++)
            acc[e2] += wgt * b2f(v8[e2]);
    }
    // reduce over the 8 k-groups (xor 8,16,32)
#pragma unroll
    for (int off = 8; off <= 32; off <<= 1)
#pragma unroll
        for (int e2 = 0; e2 < 8; e2++)
            acc[e2] += __shfl_xor(acc[e2], off);

    if (kg == 0) {
        float4 o0 = {acc[0], acc[1], acc[2], acc[3]};
        float4 o1 = {acc[4], acc[5], acc[6], acc[7]};
        float* op = out + (size_t)i * HH + hg * 8;
        *(float4*)(op)     = o0;
        *(float4*)(op + 4) = o1;
    }
}

extern "C" void kernel_launch(void* const* d_in, const int* in_sizes, int n_in,
                              void* d_out, int out_size, void* d_ws, size_t ws_size,
                              hipStream_t stream)
{
    const float* x         = (const float*)d_in[0];
    const int*   edge_type = (const int*)d_in[3];
    const float* Wq        = (const float*)d_in[4];
    const float* bq        = (const float*)d_in[5];
    const float* Wk        = (const float*)d_in[6];
    const float* bk        = (const float*)d_in[7];
    const float* Wv        = (const float*)d_in[8];
    const float* ekemb     = (const float*)d_in[9];
    float* out = (float*)d_out;

    char* ws = (char*)d_ws;
    float*          Q  = (float*)ws;                          // 2 MB
    unsigned short* Kb = (unsigned short*)(ws + (2u << 20));  // 1 MB
    unsigned short* Vb = (unsigned short*)(ws + (3u << 20));  // 1 MB
    unsigned short* Wt = (unsigned short*)(ws + (4u << 20));  // 96 KB

    prepw_kernel<<<96, 64, 0, stream>>>(Wq, Wk, Wv, Wt);
    gemm_kernel<<<2048, 256, 0, stream>>>(x, Wt, bq, bk, Q, Kb, Vb);
    attn_kernel<<<2048, 256, 0, stream>>>(Q, Kb, Vb, edge_type, ekemb, out);
}

// Round 2
// 95.916 us; speedup vs baseline: 1.0014x; 1.0014x over previous
//
#include <hip/hip_runtime.h>
#include <hip/hip_bf16.h>

#define NN 8192
#define DD 256
#define HH 64
#define DEG 32

typedef __attribute__((ext_vector_type(8))) short short8;   // 8 bf16
typedef __attribute__((ext_vector_type(4))) float f32x4;

static __device__ __forceinline__ unsigned short f2b(float f) {
    __hip_bfloat16 h = __float2bfloat16(f);   // RNE
    return *(unsigned short*)&h;
}
static __device__ __forceinline__ float b2f(unsigned short u) {
    unsigned int v = ((unsigned int)u) << 16;
    float out;
    __builtin_memcpy(&out, &v, 4);
    return out;
}

// ---------------- Kernel 1: QKV GEMM via MFMA, W transposed in-block ----------------
// 2048 blocks x 256 threads (4 waves). Output tile 16 rows x 48 cols per block.
// Each block stages its 48-col B-slice from raw f32 W into LDS bf16 (replaces
// the former prepw dispatch; W is 192 KB = L2-resident, so redundant per-block
// reads are cheap). Wave w handles K range [w*64, w*64+64) -> 2 MFMA k-steps;
// partials reduced through LDS.
// bid&511 -> m-group, bid>>9 -> n-band.
__global__ __launch_bounds__(256) void gemm_kernel(
    const float* __restrict__ x,
    const float* __restrict__ Wq, const float* __restrict__ Wk, const float* __restrict__ Wv,
    const float* __restrict__ bq, const float* __restrict__ bk,
    float* __restrict__ Q, unsigned short* __restrict__ Kb, unsigned short* __restrict__ Vb)
{
    __shared__ unsigned short WtL[48][264];  // [c-local][d], pad 256->264 (row stride 528B)
    __shared__ float part[4][768];           // per-wave 16x48 partial tiles

    const int bid = blockIdx.x;
    const int m0 = (bid & 511) * 16;
    const int n0 = (bid >> 9) * 48;

    // ---- stage B slice: cols n0..n0+47 of [Wq|Wk|Wv], transposed to [c][d] ----
    {
        const int c  = threadIdx.x & 63;      // active if < 48
        const int db = threadIdx.x >> 6;      // 0..3
        if (c < 48) {
            const int cg = n0 + c;
            const int sel = cg >> 6, cc = cg & 63;
            const float* W = (sel == 0) ? Wq : (sel == 1) ? Wk : Wv;
#pragma unroll 4
            for (int d = db; d < 256; d += 4)               // lanes coalesce over cc
                WtL[c][d] = f2b(W[d * HH + cc]);
        }
    }
    __syncthreads();

    const int w    = threadIdx.x >> 6;
    const int lane = threadIdx.x & 63;
    const int l15 = lane & 15, quad = lane >> 4;

    const float* arow = x + (size_t)(m0 + l15) * DD + w * 64 + quad * 8;

    f32x4 acc0 = {0.f,0.f,0.f,0.f}, acc1 = {0.f,0.f,0.f,0.f}, acc2 = {0.f,0.f,0.f,0.f};

#pragma unroll
    for (int ks = 0; ks < 2; ks++) {
        const int k0 = ks * 32;
        float4 xa = *(const float4*)(arow + k0);
        float4 xb = *(const float4*)(arow + k0 + 4);
        short8 a;
        a[0] = f2b(xa.x); a[1] = f2b(xa.y); a[2] = f2b(xa.z); a[3] = f2b(xa.w);
        a[4] = f2b(xb.x); a[5] = f2b(xb.y); a[6] = f2b(xb.z); a[7] = f2b(xb.w);
        const int kc = w * 64 + k0 + quad * 8;
        short8 b0 = *(const short8*)(&WtL[     l15][kc]);
        short8 b1 = *(const short8*)(&WtL[16 + l15][kc]);
        short8 b2 = *(const short8*)(&WtL[32 + l15][kc]);
        acc0 = __builtin_amdgcn_mfma_f32_16x16x32_bf16(a, b0, acc0, 0, 0, 0);
        acc1 = __builtin_amdgcn_mfma_f32_16x16x32_bf16(a, b1, acc1, 0, 0, 0);
        acc2 = __builtin_amdgcn_mfma_f32_16x16x32_bf16(a, b2, acc2, 0, 0, 0);
    }

    // Deposit partials. C layout: col = nt*16+l15, row = quad*4+r
    const f32x4 accs[3] = {acc0, acc1, acc2};
#pragma unroll
    for (int nt = 0; nt < 3; nt++)
#pragma unroll
        for (int r = 0; r < 4; r++)
            part[w][(quad * 4 + r) * 48 + nt * 16 + l15] = accs[nt][r];
    __syncthreads();

    // Reduce 4 partials + bias + convert + store. 768 outputs / 256 threads = 3 each.
    const int t = threadIdx.x;
#pragma unroll
    for (int e = 0; e < 3; e++) {
        const int f = t * 3 + e;
        const int row = f / 48, col = f % 48;
        float v = part[0][f] + part[1][f] + part[2][f] + part[3][f];
        const int cg = n0 + col;
        const size_t ro = (size_t)(m0 + row) * HH;
        if (cg < 64) {
            Q[ro + cg] = v + bq[cg];
        } else if (cg < 128) {
            const int c = cg - 64;
            Kb[ro + c] = f2b(v + bk[c]);
        } else {
            const int c = cg - 128;
            Vb[ro + c] = f2b(v);
        }
    }
}

// ---------------- Kernel 2: sparse attention ----------------
// 2048 blocks x 256 threads: 4 nodes per block, one wave per node.
// Phase2 lane=(k,half): one edge dot per lane pair.
// Phase3 lane=(kg,hg): short8 (16B) V loads, shfl-tree reduce over 8 k-groups.
__global__ __launch_bounds__(256) void attn_kernel(
    const float* __restrict__ Q,
    const unsigned short* __restrict__ Kb, const unsigned short* __restrict__ Vb,
    const int* __restrict__ edge_type, const float* __restrict__ ek_emb,
    float* __restrict__ out)
{
    __shared__ float q[4][HH];
    __shared__ float p[4][DEG];

    const int wv   = threadIdx.x >> 6;
    const int lane = threadIdx.x & 63;
    const int i = blockIdx.x * 4 + wv;
    const int k = lane >> 1, half = lane & 1;

    // issue all global loads early
    q[wv][lane] = Q[(size_t)i * HH + lane];
    const int et = edge_type[i * DEG + k];          // pair-duplicated, coalesced
    const float ekv = ek_emb[et];
    const int j = (i + 37 * (k + 1)) & (NN - 1);
    const unsigned short* kr = Kb + (size_t)j * HH + half * 32;
    short8 kv[4];
    kv[0] = *(const short8*)(kr);
    kv[1] = *(const short8*)(kr + 8);
    kv[2] = *(const short8*)(kr + 16);
    kv[3] = *(const short8*)(kr + 24);
    __syncthreads();

    // dot: lane covers h = half*32 .. half*32+31
    const float4* q4 = (const float4*)(q[wv] + half * 32);
    float s = 0.f;
#pragma unroll
    for (int c8 = 0; c8 < 4; c8++) {
        float4 qa = q4[c8 * 2];
        float4 qb = q4[c8 * 2 + 1];
        short8 kk = kv[c8];
        s += qa.x * b2f(kk[0]) + qa.y * b2f(kk[1]) + qa.z * b2f(kk[2]) + qa.w * b2f(kk[3]);
        s += qb.x * b2f(kk[4]) + qb.y * b2f(kk[5]) + qb.z * b2f(kk[6]) + qb.w * b2f(kk[7]);
    }
    s += __shfl_xor(s, 1);                  // pair-complete dot, duplicated in pair
    s = (s + ekv) * (1.0f / 512.0f);

    // softmax across the 32 ks. Butterfly over xor {2,4,8,16,32} stays within
    // one lane-parity group, and each parity group holds every k EXACTLY ONCE.
    float m = s;
#pragma unroll
    for (int off = 2; off <= 32; off <<= 1)
        m = fmaxf(m, __shfl_xor(m, off));
    float e = __expf(s - m);
    float sum = e;
#pragma unroll
    for (int off = 2; off <= 32; off <<= 1)
        sum += __shfl_xor(sum, off);
    float pk = e / sum;
    if (!half) p[wv][k] = pk;
    __syncthreads();

    // V pass: lane = (kg, hg). kg group handles k = kg*4..kg*4+3, hg covers 8 h.
    const int hg = lane & 7, kg = lane >> 3;
    float acc[8] = {0.f,0.f,0.f,0.f,0.f,0.f,0.f,0.f};
#pragma unroll
    for (int t = 0; t < 4; t++) {
        const int kk = kg * 4 + t;
        const int jj = (i + 37 * (kk + 1)) & (NN - 1);
        short8 v8 = *(const short8*)(Vb + (size_t)jj * HH + hg * 8);
        const float wgt = p[wv][kk];
#pragma unroll
        for (int e2 = 0; e2 < 8; e2++)
            acc[e2] += wgt * b2f(v8[e2]);
    }
    // reduce over the 8 k-groups (xor 8,16,32)
#pragma unroll
    for (int off = 8; off <= 32; off <<= 1)
#pragma unroll
        for (int e2 = 0; e2 < 8; e2++)
            acc[e2] += __shfl_xor(acc[e2], off);

    if (kg == 0) {
        float4 o0 = {acc[0], acc[1], acc[2], acc[3]};
        float4 o1 = {acc[4], acc[5], acc[6], acc[7]};
        float* op = out + (size_t)i * HH + hg * 8;
        *(float4*)(op)     = o0;
        *(float4*)(op + 4) = o1;
    }
}

extern "C" void kernel_launch(void* const* d_in, const int* in_sizes, int n_in,
                              void* d_out, int out_size, void* d_ws, size_t ws_size,
                              hipStream_t stream)
{
    const float* x         = (const float*)d_in[0];
    const int*   edge_type = (const int*)d_in[3];
    const float* Wq        = (const float*)d_in[4];
    const float* bq        = (const float*)d_in[5];
    const float* Wk        = (const float*)d_in[6];
    const float* bk        = (const float*)d_in[7];
    const float* Wv        = (const float*)d_in[8];
    const float* ekemb     = (const float*)d_in[9];
    float* out = (float*)d_out;

    char* ws = (char*)d_ws;
    float*          Q  = (float*)ws;                          // 2 MB
    unsigned short* Kb = (unsigned short*)(ws + (2u << 20));  // 1 MB
    unsigned short* Vb = (unsigned short*)(ws + (3u << 20));  // 1 MB

    gemm_kernel<<<2048, 256, 0, stream>>>(x, Wq, Wk, Wv, bq, bk, Q, Kb, Vb);
    attn_kernel<<<2048, 256, 0, stream>>>(Q, Kb, Vb, edge_type, ekemb, out);
}